// Round 3
// baseline (1017.537 us; speedup 1.0000x reference)
//
#include <hip/hip_runtime.h>
#include <hip/hip_bf16.h>
#include <stdint.h>

typedef __hip_bfloat16 bf16;

#define NN    4096
#define NODES 8192
#define DIM   128
#define MD    16
#define KNNK  32
#define H1N   530      // 2*265
#define PSTR  1060     // [P_i row | P_j row]

__device__ __forceinline__ float b2f(bf16 x){ return __bfloat162float(x); }
__device__ __forceinline__ bf16  f2b(float x){ return __float2bfloat16(x); }
__device__ __forceinline__ float silu_f(float x){ return x / (1.f + __expf(-x)); }

// ---------------------------------------------------------------- K0: dtype detect
// One block per tensor. Interpret buffer as bf16[n]; true-bf16 data here is
// bounded (|x| <~ 15), while fp32 data reinterpreted as bf16 yields mantissa
// halves with uniform-random exponents (|x| > 64 w.p. ~0.5 per even element).
// All-zero tensors decode identically either way, so their flag is moot.
struct Ptrs { const void* p[14]; int n[14]; };

__global__ __launch_bounds__(256) void detect_kernel(Ptrs ps, int* flags){
    int tn = blockIdx.x;
    const bf16* s = (const bf16*)ps.p[tn];
    int n = ps.n[tn]; if (n > 8192) n = 8192;
    int bad = 0;
    for (int i = threadIdx.x; i < n; i += 256){
        float v = b2f(s[i]);
        if (!(fabsf(v) <= 64.f)) bad = 1;   // catches NaN/Inf too
    }
    __shared__ int sbad;
    if (threadIdx.x == 0) sbad = 0;
    __syncthreads();
    if (bad) atomicOr(&sbad, 1);
    __syncthreads();
    if (threadIdx.x == 0) flags[tn] = sbad;   // 1 = fp32, 0 = bf16
}

// ---------------------------------------------------------------- K0b: convert to fp32
__global__ __launch_bounds__(256) void convert_kernel(const void* __restrict__ src,
                                                      float* __restrict__ dst, int n,
                                                      const int* __restrict__ flag){
    int f = *flag;
    int i = blockIdx.x * 256 + threadIdx.x;
    if (i < n)
        dst[i] = f ? ((const float*)src)[i] : b2f(((const bf16*)src)[i]);
}

// ---------------------------------------------------------------- K5: emit output
__global__ __launch_bounds__(256) void emit_kernel(const float* __restrict__ outf,
                                                   void* __restrict__ dout, int n,
                                                   const int* __restrict__ flag){
    int f = *flag;
    int i = blockIdx.x * 256 + threadIdx.x;
    if (i < n){
        if (f) ((float*)dout)[i] = outf[i];
        else   ((bf16*)dout)[i]  = f2b(outf[i]);
    }
}

// ---------------------------------------------------------------- K1: KNN
// one block per (b,i); 256 threads; each thread owns 16 candidate j's in regs.
// 32 rounds of block-argmin on packed (dist_bits<<32 | j) -> exact top_k set
// semantics incl. tie-break by smaller index.
__global__ __launch_bounds__(256) void knn_kernel(const float* __restrict__ coors,
                                                  int* __restrict__ idx_out){
    int node = blockIdx.x;
    int b = node >> 12;
    int i = node & (NN - 1);
    const float* cb = coors + (size_t)b * NN * 3;
    int t = threadIdx.x;
    int lane = t & 63, wid = t >> 6;

    float qx = cb[i*3+0], qy = cb[i*3+1], qz = cb[i*3+2];

    float dl[16];
    unsigned long long lmin = ~0ull;
    #pragma unroll
    for (int s = 0; s < 16; ++s){
        int j = (s << 8) + t;
        float dx = qx - cb[j*3+0];
        float dy = qy - cb[j*3+1];
        float dz = qz - cb[j*3+2];
        float d = dx*dx + dy*dy + dz*dz;
        dl[s] = d;
        unsigned long long p = ((unsigned long long)__float_as_uint(d) << 32) | (unsigned)j;
        if (p < lmin) lmin = p;
    }

    __shared__ unsigned long long wmin[4];
    __shared__ unsigned long long gw;

    for (int k = 0; k < KNNK; ++k){
        unsigned long long v = lmin;
        #pragma unroll
        for (int off = 32; off > 0; off >>= 1){
            unsigned long long o = __shfl_down(v, off);
            if (o < v) v = o;
        }
        if (lane == 0) wmin[wid] = v;
        __syncthreads();
        if (t == 0){
            unsigned long long g = wmin[0];
            if (wmin[1] < g) g = wmin[1];
            if (wmin[2] < g) g = wmin[2];
            if (wmin[3] < g) g = wmin[3];
            gw = g;
            idx_out[node*KNNK + k] = (int)(unsigned)(g & 0xffffffffull);
        }
        __syncthreads();
        int jw = (int)(unsigned)(gw & 0xffffffffull);
        if ((jw & 255) == t){
            dl[jw >> 8] = 3.4e38f;
            unsigned long long nm = ~0ull;
            #pragma unroll
            for (int s = 0; s < 16; ++s){
                unsigned long long p = ((unsigned long long)__float_as_uint(dl[s]) << 32)
                                       | (unsigned)((s << 8) + t);
                if (p < nm) nm = p;
            }
            lmin = nm;
        }
        // read of gw (this iter) / write of gw (next iter) separated by the
        // first __syncthreads of the next iteration.
    }
}

// ---------------------------------------------------------------- K2: P-GEMM (per batch)
// P[m][0:530]   = feats_b[m] @ We1[0:128,:]    (feats_i part)
// P[m][530:1060]= feats_b[m] @ We1[128:256,:]  (feats_j part)
__global__ __launch_bounds__(256) void p_gemm(const float* __restrict__ feats_b,
                                              const float* __restrict__ We1,
                                              bf16* __restrict__ P){
    __shared__ float As[64][68];
    __shared__ float Bs[64][68];
    int t = threadIdx.x;
    int m0 = blockIdx.x << 6;
    int n0 = blockIdx.y << 6;
    int half = blockIdx.z;
    const float* Wb = We1 + (size_t)half * DIM * H1N;

    int tr = (t >> 4) << 2;
    int tc = (t & 15) << 2;
    float acc[4][4] = {};

    for (int kk = 0; kk < DIM; kk += 64){
        for (int e = t; e < 64*64; e += 256){
            int r = e >> 6, c = e & 63;
            As[r][c] = feats_b[(size_t)(m0 + r) * DIM + kk + c];
        }
        for (int e = t; e < 64*64; e += 256){
            int r = e >> 6, c = e & 63;
            int n = n0 + c;
            Bs[r][c] = (n < H1N) ? Wb[(size_t)(kk + r) * H1N + n] : 0.f;
        }
        __syncthreads();
        #pragma unroll 8
        for (int k = 0; k < 64; ++k){
            float a0 = As[tr+0][k], a1 = As[tr+1][k], a2 = As[tr+2][k], a3 = As[tr+3][k];
            float b0 = Bs[k][tc+0], b1 = Bs[k][tc+1], b2 = Bs[k][tc+2], b3 = Bs[k][tc+3];
            acc[0][0] += a0*b0; acc[0][1] += a0*b1; acc[0][2] += a0*b2; acc[0][3] += a0*b3;
            acc[1][0] += a1*b0; acc[1][1] += a1*b1; acc[1][2] += a1*b2; acc[1][3] += a1*b3;
            acc[2][0] += a2*b0; acc[2][1] += a2*b1; acc[2][2] += a2*b2; acc[2][3] += a2*b3;
            acc[3][0] += a3*b0; acc[3][1] += a3*b1; acc[3][2] += a3*b2; acc[3][3] += a3*b3;
        }
        __syncthreads();
    }
    #pragma unroll
    for (int ii = 0; ii < 4; ++ii)
        #pragma unroll
        for (int jj = 0; jj < 4; ++jj){
            int n = n0 + tc + jj;
            if (n < H1N)
                P[(size_t)(m0 + tr + ii) * PSTR + (size_t)half * H1N + n] = f2b(acc[ii][jj]);
        }
}

// ---------------------------------------------------------------- K3: edges (per batch)
// one block per node (256 thr = 4 waves); each wave processes 8 edges.
__global__ __launch_bounds__(256) void edge_kernel(
        int b,
        const float* __restrict__ coors, const float* __restrict__ We1,
        const float* __restrict__ be1,   const float* __restrict__ We2,
        const float* __restrict__ be2,   const float* __restrict__ Wc1,
        const float* __restrict__ bc1,   const float* __restrict__ Wc2,
        const float* __restrict__ bc2,   const int*  __restrict__ idx,
        const bf16* __restrict__ P,      float* __restrict__ m_i,
        float* __restrict__ coors_out){
    __shared__ float sPi[H1N];              // P_i row + be1 folded
    __shared__ float sW1f[9 * H1N];         // fourier rows of We1 (rows 256..264)
    __shared__ bf16  sW2T[16 * 538];        // We2 transposed, padded stride
    __shared__ __align__(16) float sh1[4 * 536];  // per-wave h1
    __shared__ float sWc1[16 * 64];
    __shared__ float sbc1[64], swc2[64], sbe2[16];
    __shared__ float sMred[64];
    __shared__ float sCred[16];

    int i = blockIdx.x;                 // node within batch
    int node = (b << 12) + i;           // global node
    int t = threadIdx.x, lane = t & 63, wid = t >> 6;

    const bf16* Prow = P + (size_t)i * PSTR;
    for (int c = t; c < H1N; c += 256) sPi[c] = b2f(Prow[c]) + be1[c];
    for (int e = t; e < 9 * H1N; e += 256) sW1f[e] = We1[(size_t)256 * H1N + e];
    for (int e = t; e < H1N * 16; e += 256){
        int r = e >> 4, c = e & 15;
        sW2T[c * 538 + r] = f2b(We2[e]);
    }
    for (int e = t; e < 1024; e += 256) sWc1[e] = Wc1[e];
    if (t < 64){ sbc1[t] = bc1[t]; swc2[t] = Wc2[t]; }
    if (t < 16) sbe2[t] = be2[t];

    const float* cb = coors + (size_t)b * NN * 3;
    float qx = cb[i*3+0], qy = cb[i*3+1], qz = cb[i*3+2];
    float bc2v = bc2[0];

    float m_acc = 0.f;                 // lanes 0..15 hold m_i partials
    float cax = 0.f, cay = 0.f, caz = 0.f;
    float* h1w = sh1 + wid * 536;

    for (int e = 0; e < 8; ++e){
        __syncthreads();               // staging (e==0) / previous layer-2 reads
        int k = wid * 8 + e;
        int j = idx[node * KNNK + k];
        float rx = qx - cb[j*3+0];
        float ry = qy - cb[j*3+1];
        float rz = qz - cb[j*3+2];
        float d = rx*rx + ry*ry + rz*rz;

        // fourier features: lanes 0-3 sin(d/2^l), 4-7 cos(d/2^(l-4)), 8: d
        float xs = d * (1.f / (float)(1 << (lane & 3)));
        float my = d;
        if (lane < 4)      my = sinf(xs);
        else if (lane < 8) my = cosf(xs);
        float fe0 = __shfl(my, 0), fe1 = __shfl(my, 1), fe2 = __shfl(my, 2);
        float fe3 = __shfl(my, 3), fe4 = __shfl(my, 4), fe5 = __shfl(my, 5);
        float fe6 = __shfl(my, 6), fe7 = __shfl(my, 7), fe8 = __shfl(my, 8);

        const bf16* Pj = P + (size_t)j * PSTR + H1N;
        #pragma unroll
        for (int q = 0; q < 9; ++q){
            int c = lane + (q << 6);
            if (c < H1N){
                float v = sPi[c] + b2f(Pj[c]);
                v += fe0 * sW1f[c]           + fe1 * sW1f[H1N + c]
                   + fe2 * sW1f[2*H1N + c]   + fe3 * sW1f[3*H1N + c]
                   + fe4 * sW1f[4*H1N + c]   + fe5 * sW1f[5*H1N + c]
                   + fe6 * sW1f[6*H1N + c]   + fe7 * sW1f[7*H1N + c]
                   + fe8 * sW1f[8*H1N + c];
                h1w[c] = silu_f(v);
            }
        }
        __syncthreads();

        // layer 2: lane -> (c16 = lane&15, chunk = lane>>4); pair reads
        int c16 = lane & 15, ch = lane >> 4;
        int r0 = ch * 134;
        int rend = (530 < r0 + 134) ? 530 : (r0 + 134);
        const bf16* wrow = sW2T + c16 * 538;
        float acc = 0.f;
        for (int r = r0; r < rend; r += 2){
            __hip_bfloat162 wp = *(const __hip_bfloat162*)(wrow + r);
            float2 wf = __bfloat1622float2(wp);
            float2 hf = *(const float2*)(h1w + r);
            acc += hf.x * wf.x + hf.y * wf.y;
        }
        acc += __shfl_down(acc, 32);
        acc += __shfl_down(acc, 16);
        float m = silu_f(acc + sbe2[c16]);   // valid on lanes 0..15
        if (lane < 16) m_acc += m;

        // coors weight: hid[u] (u = lane), then full-wave reduce
        float hacc = sbc1[lane];
        #pragma unroll
        for (int c = 0; c < 16; ++c)
            hacc += __shfl(m, c) * sWc1[(c << 6) + lane];
        float hid = silu_f(hacc);
        float term = hid * swc2[lane];
        #pragma unroll
        for (int off = 32; off > 0; off >>= 1)
            term += __shfl_xor(term, off);
        float cw = term + bc2v;
        cax += cw * rx; cay += cw * ry; caz += cw * rz;
    }

    __syncthreads();
    if (lane < 16) sMred[wid * 16 + lane] = m_acc;
    if (lane == 0){
        sCred[wid*4+0] = cax; sCred[wid*4+1] = cay; sCred[wid*4+2] = caz;
    }
    __syncthreads();
    if (t < 16){
        float s = sMred[t] + sMred[16 + t] + sMred[32 + t] + sMred[48 + t];
        m_i[node * MD + t] = s;
    }
    if (t < 3){
        float s = sCred[t] + sCred[4 + t] + sCred[8 + t] + sCred[12 + t];
        float base = (t == 0) ? qx : (t == 1) ? qy : qz;
        coors_out[node * 3 + t] = s + base;
    }
}

// ---------------------------------------------------------------- K4: node MLP
// 8 nodes per block; x = [feats | m_i] (144), h = silu(x@Wn1+bn1) (256),
// out = h@Wn2 + bn2 + feats.
__global__ __launch_bounds__(256) void node_kernel(
        const float* __restrict__ feats, const float* __restrict__ m_i,
        const float* __restrict__ Wn1,   const float* __restrict__ bn1,
        const float* __restrict__ Wn2,   const float* __restrict__ bn2,
        float* __restrict__ out){
    __shared__ float X[8][144];
    __shared__ float Hs[8][256];
    int t = threadIdx.x;
    int g0 = blockIdx.x << 3;

    for (int e = t; e < 8 * DIM; e += 256){
        int nd = e >> 7, c = e & 127;
        X[nd][c] = feats[(size_t)(g0 + nd) * DIM + c];
    }
    if (t < 128){
        int nd = t >> 4, c = t & 15;
        X[nd][DIM + c] = m_i[(size_t)(g0 + nd) * MD + c];
    }
    __syncthreads();

    float acc[8] = {};
    for (int r = 0; r < 144; ++r){
        float w = Wn1[(size_t)r * 256 + t];
        #pragma unroll
        for (int nd = 0; nd < 8; ++nd) acc[nd] += X[nd][r] * w;
    }
    float bb = bn1[t];
    #pragma unroll
    for (int nd = 0; nd < 8; ++nd) Hs[nd][t] = silu_f(acc[nd] + bb);
    __syncthreads();

    int c = t & 127, g = t >> 7;
    float a2[4] = {};
    for (int r = 0; r < 256; ++r){
        float w = Wn2[(size_t)r * DIM + c];
        #pragma unroll
        for (int u = 0; u < 4; ++u) a2[u] += Hs[g*4 + u][r] * w;
    }
    float b2v = bn2[c];
    #pragma unroll
    for (int u = 0; u < 4; ++u){
        int nd = g*4 + u;
        out[(size_t)(g0 + nd) * DIM + c] = a2[u] + b2v + X[nd][c];
    }
}

// ---------------------------------------------------------------- launch
extern "C" void kernel_launch(void* const* d_in, const int* in_sizes, int n_in,
                              void* d_out, int out_size, void* d_ws, size_t ws_size,
                              hipStream_t stream){
    char* ws = (char*)d_ws;
    size_t off = 0;
    auto alloc = [&](size_t bytes) -> char* {
        off = (off + 511) & ~(size_t)511;
        char* p = ws + off;
        off += bytes;
        return p;
    };

    int*   flags  = (int*)  alloc(14 * 4);
    float* conv[14];
    for (int i = 0; i < 14; ++i) conv[i] = (float*)alloc((size_t)in_sizes[i] * 4);
    int*   idx    = (int*)  alloc((size_t)NODES * KNNK * 4);
    bf16*  P      = (bf16*) alloc((size_t)NN * PSTR * 2);     // reused per batch
    float* mi     = (float*)alloc((size_t)NODES * MD * 4);
    float* outf   = (float*)alloc((size_t)out_size * 4);

    // K0: per-tensor dtype detection (1 = fp32, 0 = bf16)
    Ptrs ps;
    for (int i = 0; i < 14; ++i){ ps.p[i] = d_in[i]; ps.n[i] = in_sizes[i]; }
    detect_kernel<<<14, 256, 0, stream>>>(ps, flags);

    // K0b: convert every input to fp32 working copies
    for (int i = 0; i < 14; ++i){
        int n = in_sizes[i];
        convert_kernel<<<(n + 255) / 256, 256, 0, stream>>>(d_in[i], conv[i], n, flags + i);
    }

    const float* feats = conv[0];
    const float* coors = conv[1];
    const float* We1 = conv[2],  * be1 = conv[3];
    const float* We2 = conv[4],  * be2 = conv[5];
    const float* Wc1 = conv[6],  * bc1 = conv[7];
    const float* Wc2 = conv[8],  * bc2 = conv[9];
    const float* Wn1 = conv[10], * bn1 = conv[11];
    const float* Wn2 = conv[12], * bn2 = conv[13];

    knn_kernel<<<NODES, 256, 0, stream>>>(coors, idx);
    for (int b = 0; b < 2; ++b){
        p_gemm<<<dim3(64, 9, 2), 256, 0, stream>>>(feats + (size_t)b * NN * DIM, We1, P);
        edge_kernel<<<NN, 256, 0, stream>>>(b, coors, We1, be1, We2, be2, Wc1, bc1,
                                            Wc2, bc2, idx, P, mi,
                                            outf + (size_t)NODES * DIM);
    }
    node_kernel<<<1024, 256, 0, stream>>>(feats, mi, Wn1, bn1, Wn2, bn2, outf);

    // K5: emit d_out in the detected dtype (mode follows feats)
    emit_kernel<<<(out_size + 255) / 256, 256, 0, stream>>>(outf, d_out, out_size, flags + 0);
}

// Round 4
// 573.178 us; speedup vs baseline: 1.7753x; 1.7753x over previous
//
#include <hip/hip_runtime.h>
#include <hip/hip_bf16.h>
#include <stdint.h>

typedef __hip_bfloat16 bf16;

using sh8   = __attribute__((ext_vector_type(8)))  short;
using sh4   = __attribute__((ext_vector_type(4)))  short;
using us4   = __attribute__((ext_vector_type(4)))  unsigned short;
using f32x16 = __attribute__((ext_vector_type(16))) float;
using fx4   = __attribute__((ext_vector_type(4)))  float;

#define NN    4096
#define NODES 8192
#define DIM   128
#define MD    16
#define KNNK  32
#define H1N   530
#define CPAD  544      // H1N padded to 17*32
#define PROW  1088     // [Pi 544 | Pj 544] per node, bf16

__device__ __forceinline__ float b2f(bf16 x){ return __bfloat162float(x); }
__device__ __forceinline__ bf16  f2b(float x){ return __float2bfloat16(x); }
__device__ __forceinline__ float silu_f(float x){ return x / (1.f + __expf(-x)); }

// fp32 -> bf16 bits (RNE), and back
__device__ __forceinline__ unsigned short f2us(float f){
    unsigned x = __float_as_uint(f);
    unsigned r = x + 0x7FFFu + ((x >> 16) & 1u);
    return (unsigned short)(r >> 16);
}
__device__ __forceinline__ float us2f(unsigned short u){
    return __uint_as_float(((unsigned)u) << 16);
}

// ---------------------------------------------------------------- K0: dtype detect
struct Ptrs { const void* p[14]; int n[14]; };

__global__ __launch_bounds__(256) void detect_kernel(Ptrs ps, int* flags){
    int tn = blockIdx.x;
    const bf16* s = (const bf16*)ps.p[tn];
    int n = ps.n[tn]; if (n > 8192) n = 8192;
    int bad = 0;
    for (int i = threadIdx.x; i < n; i += 256){
        float v = b2f(s[i]);
        if (!(fabsf(v) <= 64.f)) bad = 1;   // catches NaN/Inf too
    }
    __shared__ int sbad;
    if (threadIdx.x == 0) sbad = 0;
    __syncthreads();
    if (bad) atomicOr(&sbad, 1);
    __syncthreads();
    if (threadIdx.x == 0) flags[tn] = sbad;   // 1 = fp32, 0 = bf16
}

// ---------------------------------------------------------------- K0b: convert to fp32
__global__ __launch_bounds__(256) void convert_kernel(const void* __restrict__ src,
                                                      float* __restrict__ dst, int n,
                                                      const int* __restrict__ flag){
    int f = *flag;
    int i = blockIdx.x * 256 + threadIdx.x;
    if (i < n)
        dst[i] = f ? ((const float*)src)[i] : b2f(((const bf16*)src)[i]);
}

// ---------------------------------------------------------------- K5: emit output
__global__ __launch_bounds__(256) void emit_kernel(const float* __restrict__ outf,
                                                   void* __restrict__ dout, int n,
                                                   const int* __restrict__ flag){
    int f = *flag;
    int i = blockIdx.x * 256 + threadIdx.x;
    if (i < n){
        if (f) ((float*)dout)[i] = outf[i];
        else   ((bf16*)dout)[i]  = f2b(outf[i]);
    }
}

// ---------------------------------------------------------------- K1: KNN (unchanged, verified)
__global__ __launch_bounds__(256) void knn_kernel(const float* __restrict__ coors,
                                                  int* __restrict__ idx_out){
    int node = blockIdx.x;
    int b = node >> 12;
    int i = node & (NN - 1);
    const float* cb = coors + (size_t)b * NN * 3;
    int t = threadIdx.x;
    int lane = t & 63, wid = t >> 6;

    float qx = cb[i*3+0], qy = cb[i*3+1], qz = cb[i*3+2];

    float dl[16];
    unsigned long long lmin = ~0ull;
    #pragma unroll
    for (int s = 0; s < 16; ++s){
        int j = (s << 8) + t;
        float dx = qx - cb[j*3+0];
        float dy = qy - cb[j*3+1];
        float dz = qz - cb[j*3+2];
        float d = dx*dx + dy*dy + dz*dz;
        dl[s] = d;
        unsigned long long p = ((unsigned long long)__float_as_uint(d) << 32) | (unsigned)j;
        if (p < lmin) lmin = p;
    }

    __shared__ unsigned long long wmin[4];
    __shared__ unsigned long long gw;

    for (int k = 0; k < KNNK; ++k){
        unsigned long long v = lmin;
        #pragma unroll
        for (int off = 32; off > 0; off >>= 1){
            unsigned long long o = __shfl_down(v, off);
            if (o < v) v = o;
        }
        if (lane == 0) wmin[wid] = v;
        __syncthreads();
        if (t == 0){
            unsigned long long g = wmin[0];
            if (wmin[1] < g) g = wmin[1];
            if (wmin[2] < g) g = wmin[2];
            if (wmin[3] < g) g = wmin[3];
            gw = g;
            idx_out[node*KNNK + k] = (int)(unsigned)(g & 0xffffffffull);
        }
        __syncthreads();
        int jw = (int)(unsigned)(gw & 0xffffffffull);
        if ((jw & 255) == t){
            dl[jw >> 8] = 3.4e38f;
            unsigned long long nm = ~0ull;
            #pragma unroll
            for (int s = 0; s < 16; ++s){
                unsigned long long p = ((unsigned long long)__float_as_uint(dl[s]) << 32)
                                       | (unsigned)((s << 8) + t);
                if (p < nm) nm = p;
            }
            lmin = nm;
        }
    }
}

// ---------------------------------------------------------------- K2: P-GEMM (per batch)
// P[m][0:544]    = feats_b[m] @ We1[0:128,:]   (zero-padded cols 530..543)
// P[m][544:1088] = feats_b[m] @ We1[128:256,:]
__global__ __launch_bounds__(256) void p_gemm(const float* __restrict__ feats_b,
                                              const float* __restrict__ We1,
                                              unsigned short* __restrict__ P){
    __shared__ float As[64][68];
    __shared__ float Bs[64][68];
    int t = threadIdx.x;
    int m0 = blockIdx.x << 6;
    int n0 = blockIdx.y << 6;
    int half = blockIdx.z;
    const float* Wb = We1 + (size_t)half * DIM * H1N;

    int tr = (t >> 4) << 2;
    int tc = (t & 15) << 2;
    float acc[4][4] = {};

    for (int kk = 0; kk < DIM; kk += 64){
        for (int e = t; e < 64*64; e += 256){
            int r = e >> 6, c = e & 63;
            As[r][c] = feats_b[(size_t)(m0 + r) * DIM + kk + c];
        }
        for (int e = t; e < 64*64; e += 256){
            int r = e >> 6, c = e & 63;
            int n = n0 + c;
            Bs[r][c] = (n < H1N) ? Wb[(size_t)(kk + r) * H1N + n] : 0.f;
        }
        __syncthreads();
        #pragma unroll 8
        for (int k = 0; k < 64; ++k){
            float a0 = As[tr+0][k], a1 = As[tr+1][k], a2 = As[tr+2][k], a3 = As[tr+3][k];
            float b0 = Bs[k][tc+0], b1 = Bs[k][tc+1], b2 = Bs[k][tc+2], b3 = Bs[k][tc+3];
            acc[0][0] += a0*b0; acc[0][1] += a0*b1; acc[0][2] += a0*b2; acc[0][3] += a0*b3;
            acc[1][0] += a1*b0; acc[1][1] += a1*b1; acc[1][2] += a1*b2; acc[1][3] += a1*b3;
            acc[2][0] += a2*b0; acc[2][1] += a2*b1; acc[2][2] += a2*b2; acc[2][3] += a2*b3;
            acc[3][0] += a3*b0; acc[3][1] += a3*b1; acc[3][2] += a3*b2; acc[3][3] += a3*b3;
        }
        __syncthreads();
    }
    #pragma unroll
    for (int ii = 0; ii < 4; ++ii)
        #pragma unroll
        for (int jj = 0; jj < 4; ++jj){
            int n = n0 + tc + jj;
            if (n < CPAD)   // cols 530..543 get exact 0 (Bs was zero there)
                P[(size_t)(m0 + tr + ii) * PROW + (size_t)half * CPAD + n] = f2us(acc[ii][jj]);
        }
}

// ---------------------------------------------------------------- K3: edges (MFMA, per batch)
// 4 nodes/block, 1 wave/node, all main-loop LDS traffic is intra-wave.
__global__ __launch_bounds__(256, 3) void edge_kernel(
        int b,
        const float* __restrict__ coors, const float* __restrict__ We1,
        const float* __restrict__ be1,   const float* __restrict__ We2,
        const float* __restrict__ be2,   const float* __restrict__ Wc1,
        const float* __restrict__ bc1,   const float* __restrict__ Wc2,
        const float* __restrict__ bc2,   const int*  __restrict__ idx,
        const unsigned short* __restrict__ P, float* __restrict__ mi_out,
        float* __restrict__ coors_out){
    // weights (per block)
    __shared__ unsigned short sW1fA[CPAD * 8];   // [c][f=0..7] bf16, A-frag rows for lo half
    __shared__ unsigned short sW1f8[CPAD];       // f=8 row
    __shared__ unsigned short sWe2A[16 * 552];   // [o][c] bf16, phase-D A
    __shared__ float          sbe1[CPAD];
    __shared__ unsigned short sWc1A[64 * 32];    // [u][k] bf16 (k<16 real), phase-E A
    __shared__ float sbc1v[64], swc2v[64], sbe2v[16];
    // per-node (per wave)
    __shared__ unsigned short sFeT[4][32 * 16];  // [e][f] bf16 (f 9..15 = 0)
    __shared__ unsigned short trans[4][32 * 40]; // [e][c_local] bf16, chunk transpose buf
    __shared__ unsigned short sM[4][32 * 16];    // [e][o] bf16

    int t = threadIdx.x, lane = t & 63, wid = t >> 6;
    int i = (blockIdx.x << 2) + wid;      // batch-local node
    int gnode = (b << 12) + i;

    // ---- stage weights (cross-wave; barrier below) ----
    for (int e = t; e < CPAD * 8; e += 256){
        int c = e >> 3, f = e & 7;
        sW1fA[e] = (c < H1N) ? f2us(We1[(size_t)(256 + f) * H1N + c]) : 0;
    }
    for (int e = t; e < CPAD; e += 256){
        sW1f8[e] = (e < H1N) ? f2us(We1[(size_t)264 * H1N + e]) : 0;
        sbe1[e]  = (e < H1N) ? be1[e] : 0.f;
    }
    for (int o = 0; o < 16; ++o)
        for (int c = t; c < 552; c += 256)
            sWe2A[o * 552 + c] = (c < H1N) ? f2us(We2[(size_t)c * 16 + o]) : 0;
    for (int e = t; e < 64 * 32; e += 256){
        int u = e >> 5, k = e & 31;
        sWc1A[e] = (k < 16) ? f2us(Wc1[(size_t)k * 64 + u]) : 0;
    }
    if (t < 64){ sbc1v[t] = bc1[t]; swc2v[t] = Wc2[t]; }
    if (t < 16) sbe2v[t] = be2[t];

    // ---- phase A: per-edge geometry + fourier (lanes 0..31) ----
    const float* cb = coors + (size_t)b * NN * 3;
    float qx = cb[i*3+0], qy = cb[i*3+1], qz = cb[i*3+2];
    int jme = 0; float rx = 0.f, ry = 0.f, rz = 0.f;
    if (lane < 32){
        jme = idx[(size_t)gnode * KNNK + lane];
        rx = qx - cb[jme*3+0]; ry = qy - cb[jme*3+1]; rz = qz - cb[jme*3+2];
        float d = rx*rx + ry*ry + rz*rz;
        unsigned short fr[16];
        fr[0] = f2us(sinf(d));         fr[1] = f2us(sinf(d * 0.5f));
        fr[2] = f2us(sinf(d * 0.25f)); fr[3] = f2us(sinf(d * 0.125f));
        fr[4] = f2us(cosf(d));         fr[5] = f2us(cosf(d * 0.5f));
        fr[6] = f2us(cosf(d * 0.25f)); fr[7] = f2us(cosf(d * 0.125f));
        fr[8] = f2us(d);
        #pragma unroll
        for (int z = 9; z < 16; ++z) fr[z] = 0;
        unsigned short* dst = &sFeT[wid][lane * 16];
        #pragma unroll
        for (int g = 0; g < 4; ++g)
            *(sh4*)&dst[g*4] = *(const sh4*)&fr[g*4];
    }
    int jall = __shfl(jme, lane & 31);   // j for edge = lane&31, on all 64 lanes
    __syncthreads();                     // weights + sFeT visible

    const unsigned short* Pirow = P + (size_t)i * PROW;
    const unsigned short* Pjrow = P + (size_t)jall * PROW + CPAD;

    int e31 = lane & 31, hi = lane >> 5;   // phase-C roles
    int e15 = lane & 15, q  = lane >> 4;   // phase-D/E roles

    fx4 accD0 = {0.f,0.f,0.f,0.f};
    fx4 accD1 = {0.f,0.f,0.f,0.f};

    for (int ch = 0; ch < 17; ++ch){
        int c0 = ch * 32;
        // phase-C A-frag: A[c=lane&31][k=hi*8+j] = W1f[k][c] (k=8 real on hi, rest 0)
        sh8 afrag;
        if (hi == 0) afrag = *(const sh8*)&sW1fA[(size_t)(c0 + e31) * 8];
        else { afrag = (sh8)0; afrag[0] = (short)sW1f8[c0 + e31]; }
        // phase-C B-frag: B[k][e=lane&31] = fe[e][k]
        sh8 bfrag = *(const sh8*)&sFeT[wid][e31 * 16 + hi * 8];
        // C-init = Pi + Pj + be1 in 32x32 C layout (row c_local = (r&3)+8g+4*hi)
        f32x16 cc;
        #pragma unroll
        for (int g = 0; g < 4; ++g){
            int cb4 = c0 + 8*g + 4*hi;
            us4 piu = *(const us4*)(Pirow + cb4);
            us4 pju = *(const us4*)(Pjrow + cb4);
            fx4 be  = *(const fx4*)&sbe1[cb4];
            cc[4*g+0] = us2f(piu.x) + us2f(pju.x) + be.x;
            cc[4*g+1] = us2f(piu.y) + us2f(pju.y) + be.y;
            cc[4*g+2] = us2f(piu.z) + us2f(pju.z) + be.z;
            cc[4*g+3] = us2f(piu.w) + us2f(pju.w) + be.w;
        }
        f32x16 h = __builtin_amdgcn_mfma_f32_32x32x16_bf16(afrag, bfrag, cc, 0, 0, 0);
        // silu -> bf16 -> transpose buffer [e][c_local], row stride 40 shorts (80 B)
        #pragma unroll
        for (int g = 0; g < 4; ++g){
            sh4 w4;
            w4[0] = (short)f2us(silu_f(h[4*g+0]));
            w4[1] = (short)f2us(silu_f(h[4*g+1]));
            w4[2] = (short)f2us(silu_f(h[4*g+2]));
            w4[3] = (short)f2us(silu_f(h[4*g+3]));
            *(sh4*)&trans[wid][e31 * 40 + 8*g + 4*hi] = w4;
        }
        asm volatile("s_waitcnt lgkmcnt(0)" ::: "memory");  // intra-wave LDS RAW
        // phase D: OUT2[o][e] += We2T[o][c-chunk] @ h1[c-chunk][e]
        sh8 wa  = *(const sh8*)&sWe2A[e15 * 552 + c0 + q * 8];
        sh8 bt0 = *(const sh8*)&trans[wid][e15 * 40 + q * 8];
        sh8 bt1 = *(const sh8*)&trans[wid][(16 + e15) * 40 + q * 8];
        accD0 = __builtin_amdgcn_mfma_f32_16x16x32_bf16(wa, bt0, accD0, 0, 0, 0);
        accD1 = __builtin_amdgcn_mfma_f32_16x16x32_bf16(wa, bt1, accD1, 0, 0, 0);
    }

    // ---- m = silu(OUT2 + be2); write sM; m_i butterfly ----
    fx4 be2q = *(const fx4*)&sbe2v[q * 4];
    float msum[4];
    sh4 m0s, m1s;
    #pragma unroll
    for (int r = 0; r < 4; ++r){
        float mv0 = silu_f(accD0[r] + be2q[r]);
        float mv1 = silu_f(accD1[r] + be2q[r]);
        m0s[r] = (short)f2us(mv0);
        m1s[r] = (short)f2us(mv1);
        msum[r] = mv0 + mv1;
    }
    *(sh4*)&sM[wid][e15 * 16 + q * 4]        = m0s;
    *(sh4*)&sM[wid][(16 + e15) * 16 + q * 4] = m1s;
    #pragma unroll
    for (int r = 0; r < 4; ++r){
        msum[r] += __shfl_xor(msum[r], 1);
        msum[r] += __shfl_xor(msum[r], 2);
        msum[r] += __shfl_xor(msum[r], 4);
        msum[r] += __shfl_xor(msum[r], 8);
    }
    if (e15 == 0){
        fx4 mv = { msum[0], msum[1], msum[2], msum[3] };
        *(fx4*)(mi_out + (size_t)gnode * MD + q * 4) = mv;
    }
    asm volatile("s_waitcnt lgkmcnt(0)" ::: "memory");      // sM RAW

    // ---- phase E: hid^T[u][e] = Wc1T @ m^T; cw = silu(hid)·wc2 + bc2 ----
    float tsum0 = 0.f, tsum1 = 0.f;
    #pragma unroll
    for (int ut = 0; ut < 4; ++ut){
        sh8 wa3 = *(const sh8*)&sWc1A[(ut * 16 + e15) * 32 + q * 8];
        sh8 b0  = (q < 2) ? *(const sh8*)&sM[wid][e15 * 16 + q * 8]        : (sh8)0;
        sh8 b1  = (q < 2) ? *(const sh8*)&sM[wid][(16 + e15) * 16 + q * 8] : (sh8)0;
        fx4 a0 = {0.f,0.f,0.f,0.f};
        fx4 a1 = {0.f,0.f,0.f,0.f};
        a0 = __builtin_amdgcn_mfma_f32_16x16x32_bf16(wa3, b0, a0, 0, 0, 0);
        a1 = __builtin_amdgcn_mfma_f32_16x16x32_bf16(wa3, b1, a1, 0, 0, 0);
        fx4 bc1q = *(const fx4*)&sbc1v[ut * 16 + q * 4];
        fx4 wcq  = *(const fx4*)&swc2v[ut * 16 + q * 4];
        #pragma unroll
        for (int r = 0; r < 4; ++r){
            tsum0 += silu_f(a0[r] + bc1q[r]) * wcq[r];
            tsum1 += silu_f(a1[r] + bc1q[r]) * wcq[r];
        }
    }
    tsum0 += __shfl_xor(tsum0, 16); tsum0 += __shfl_xor(tsum0, 32);
    tsum1 += __shfl_xor(tsum1, 16); tsum1 += __shfl_xor(tsum1, 32);
    float cw = ((lane < 16) ? tsum0 : tsum1) + bc2[0];   // correct for lanes 0..31

    // ---- coors accumulation: lanes 0..31 hold rel for edge = lane ----
    float cx = cw * rx, cy = cw * ry, cz = cw * rz;      // 0 on lanes >= 32
    #pragma unroll
    for (int off = 1; off <= 32; off <<= 1){
        cx += __shfl_xor(cx, off);
        cy += __shfl_xor(cy, off);
        cz += __shfl_xor(cz, off);
    }
    if (lane == 0){
        coors_out[(size_t)gnode * 3 + 0] = cx + qx;
        coors_out[(size_t)gnode * 3 + 1] = cy + qy;
        coors_out[(size_t)gnode * 3 + 2] = cz + qz;
    }
}

// ---------------------------------------------------------------- K4: node MLP (unchanged)
__global__ __launch_bounds__(256) void node_kernel(
        const float* __restrict__ feats, const float* __restrict__ m_i,
        const float* __restrict__ Wn1,   const float* __restrict__ bn1,
        const float* __restrict__ Wn2,   const float* __restrict__ bn2,
        float* __restrict__ out){
    __shared__ float X[8][144];
    __shared__ float Hs[8][256];
    int t = threadIdx.x;
    int g0 = blockIdx.x << 3;

    for (int e = t; e < 8 * DIM; e += 256){
        int nd = e >> 7, c = e & 127;
        X[nd][c] = feats[(size_t)(g0 + nd) * DIM + c];
    }
    if (t < 128){
        int nd = t >> 4, c = t & 15;
        X[nd][DIM + c] = m_i[(size_t)(g0 + nd) * MD + c];
    }
    __syncthreads();

    float acc[8] = {};
    for (int r = 0; r < 144; ++r){
        float w = Wn1[(size_t)r * 256 + t];
        #pragma unroll
        for (int nd = 0; nd < 8; ++nd) acc[nd] += X[nd][r] * w;
    }
    float bb = bn1[t];
    #pragma unroll
    for (int nd = 0; nd < 8; ++nd) Hs[nd][t] = silu_f(acc[nd] + bb);
    __syncthreads();

    int c = t & 127, g = t >> 7;
    float a2[4] = {};
    for (int r = 0; r < 256; ++r){
        float w = Wn2[(size_t)r * DIM + c];
        #pragma unroll
        for (int u = 0; u < 4; ++u) a2[u] += Hs[g*4 + u][r] * w;
    }
    float b2v = bn2[c];
    #pragma unroll
    for (int u = 0; u < 4; ++u){
        int nd = g*4 + u;
        out[(size_t)(g0 + nd) * DIM + c] = a2[u] + b2v + X[nd][c];
    }
}

// ---------------------------------------------------------------- launch
extern "C" void kernel_launch(void* const* d_in, const int* in_sizes, int n_in,
                              void* d_out, int out_size, void* d_ws, size_t ws_size,
                              hipStream_t stream){
    char* ws = (char*)d_ws;
    size_t off = 0;
    auto alloc = [&](size_t bytes) -> char* {
        off = (off + 511) & ~(size_t)511;
        char* p = ws + off;
        off += bytes;
        return p;
    };

    int*   flags  = (int*)  alloc(14 * 4);
    float* conv[14];
    for (int i = 0; i < 14; ++i) conv[i] = (float*)alloc((size_t)in_sizes[i] * 4);
    int*   idx    = (int*)  alloc((size_t)NODES * KNNK * 4);
    unsigned short* P = (unsigned short*) alloc((size_t)NN * PROW * 2);  // reused per batch
    float* mi     = (float*)alloc((size_t)NODES * MD * 4);
    float* outf   = (float*)alloc((size_t)out_size * 4);

    Ptrs ps;
    for (int i = 0; i < 14; ++i){ ps.p[i] = d_in[i]; ps.n[i] = in_sizes[i]; }
    detect_kernel<<<14, 256, 0, stream>>>(ps, flags);

    for (int i = 0; i < 14; ++i){
        int n = in_sizes[i];
        convert_kernel<<<(n + 255) / 256, 256, 0, stream>>>(d_in[i], conv[i], n, flags + i);
    }

    const float* feats = conv[0];
    const float* coors = conv[1];
    const float* We1 = conv[2],  * be1 = conv[3];
    const float* We2 = conv[4],  * be2 = conv[5];
    const float* Wc1 = conv[6],  * bc1 = conv[7];
    const float* Wc2 = conv[8],  * bc2 = conv[9];
    const float* Wn1 = conv[10], * bn1 = conv[11];
    const float* Wn2 = conv[12], * bn2 = conv[13];

    knn_kernel<<<NODES, 256, 0, stream>>>(coors, idx);
    for (int b = 0; b < 2; ++b){
        p_gemm<<<dim3(64, 9, 2), 256, 0, stream>>>(feats + (size_t)b * NN * DIM, We1, P);
        edge_kernel<<<NN/4, 256, 0, stream>>>(b, coors, We1, be1, We2, be2, Wc1, bc1,
                                              Wc2, bc2, idx, P, mi,
                                              outf + (size_t)NODES * DIM);
    }
    node_kernel<<<1024, 256, 0, stream>>>(feats, mi, Wn1, bn1, Wn2, bn2, outf);

    emit_kernel<<<(out_size + 255) / 256, 256, 0, stream>>>(outf, d_out, out_size, flags + 0);
}

// Round 5
// 462.122 us; speedup vs baseline: 2.2019x; 1.2403x over previous
//
#include <hip/hip_runtime.h>
#include <hip/hip_bf16.h>
#include <stdint.h>

typedef __hip_bfloat16 bf16;

using sh8   = __attribute__((ext_vector_type(8)))  short;
using sh4   = __attribute__((ext_vector_type(4)))  short;
using us4   = __attribute__((ext_vector_type(4)))  unsigned short;
using f32x16 = __attribute__((ext_vector_type(16))) float;
using fx4   = __attribute__((ext_vector_type(4)))  float;

#define NN    4096
#define NODES 8192
#define DIM   128
#define MD    16
#define KNNK  32
#define H1N   530
#define CPAD  544      // H1N padded to 17*32
#define PROW  1088     // [Pi 544 | Pj 544] per node, bf16

__device__ __forceinline__ float b2f(bf16 x){ return __bfloat162float(x); }
__device__ __forceinline__ bf16  f2b(float x){ return __float2bfloat16(x); }
__device__ __forceinline__ float silu_f(float x){ return x / (1.f + __expf(-x)); }

__device__ __forceinline__ unsigned short f2us(float f){
    unsigned x = __float_as_uint(f);
    unsigned r = x + 0x7FFFu + ((x >> 16) & 1u);
    return (unsigned short)(r >> 16);
}
__device__ __forceinline__ float us2f(unsigned short u){
    return __uint_as_float(((unsigned)u) << 16);
}

// ---------------------------------------------------------------- K0: dtype detect
struct Ptrs { const void* p[14]; int n[14]; };

__global__ __launch_bounds__(256) void detect_kernel(Ptrs ps, int* flags){
    int tn = blockIdx.x;
    const bf16* s = (const bf16*)ps.p[tn];
    int n = ps.n[tn]; if (n > 8192) n = 8192;
    int bad = 0;
    for (int i = threadIdx.x; i < n; i += 256){
        float v = b2f(s[i]);
        if (!(fabsf(v) <= 64.f)) bad = 1;   // catches NaN/Inf too
    }
    __shared__ int sbad;
    if (threadIdx.x == 0) sbad = 0;
    __syncthreads();
    if (bad) atomicOr(&sbad, 1);
    __syncthreads();
    if (threadIdx.x == 0) flags[tn] = sbad;   // 1 = fp32, 0 = bf16
}

// ---------------------------------------------------------------- K0b: fused convert (all 14 tensors)
struct ConvTab {
    const void* src[14];
    int dstoff[14];    // element offset into conv base
    int prefix[15];    // global element prefix sums; prefix[14] = total
};

__global__ __launch_bounds__(256) void convert_all(ConvTab tab,
                                                   const int* __restrict__ flags,
                                                   float* __restrict__ base){
    int gid = blockIdx.x * 256 + threadIdx.x;
    if (gid >= tab.prefix[14]) return;
    int tn = 0;
    #pragma unroll
    for (int k = 1; k < 14; ++k)
        if (gid >= tab.prefix[k]) tn = k;
    int local = gid - tab.prefix[tn];
    int f = flags[tn];
    float v = f ? ((const float*)tab.src[tn])[local]
                : b2f(((const bf16*)tab.src[tn])[local]);
    base[tab.dstoff[tn] + local] = v;
}

// ---------------------------------------------------------------- K5: emit output
__global__ __launch_bounds__(256) void emit_kernel(const float* __restrict__ outf,
                                                   void* __restrict__ dout, int n,
                                                   const int* __restrict__ flag){
    int f = *flag;
    int i = blockIdx.x * 256 + threadIdx.x;
    if (i < n){
        if (f) ((float*)dout)[i] = outf[i];
        else   ((bf16*)dout)[i]  = f2b(outf[i]);
    }
}

// ---------------------------------------------------------------- K1: KNN via radix select
// One block per (b,i); 256 threads x 16 candidates. 4 passes of 8-bit radix
// on key4 = bits(d^4) (monotone in d; spreads exponents to de-hotspot the
// histogram). Boundary group (key4 == T4) resolved exactly in (d_bits, j)
// order -> selected set identical to jax.lax.top_k(-d, 32).
__global__ __launch_bounds__(256) void knn_kernel(const float* __restrict__ coors,
                                                  int* __restrict__ idx_out){
    __shared__ unsigned hist[4][256];       // per-wave privatized
    __shared__ unsigned sSel, sBelow;
    __shared__ int  sOcnt;
    __shared__ unsigned long long wred64[4];
    __shared__ unsigned long long sWin64;

    int node = blockIdx.x;
    int b = node >> 12, i = node & (NN - 1);
    const float* cb = coors + (size_t)b * NN * 3;
    int t = threadIdx.x, lane = t & 63, wid = t >> 6;

    float qx = cb[i*3+0], qy = cb[i*3+1], qz = cb[i*3+2];

    unsigned db[16];   // fp32 bits of d (exact reference ordering incl. ties)
    unsigned k4[16];   // fp32 bits of d^4 (radix key)
    #pragma unroll
    for (int s = 0; s < 16; ++s){
        int j = (s << 8) + t;
        float dx = qx - cb[j*3+0];
        float dy = qy - cb[j*3+1];
        float dz = qz - cb[j*3+2];
        float d  = dx*dx + dy*dy + dz*dz;
        float d2 = d * d;
        db[s] = __float_as_uint(d);
        k4[s] = __float_as_uint(d2 * d2);
    }

    unsigned prefix = 0, need = KNNK;
    #pragma unroll
    for (int p = 0; p < 4; ++p){
        const int shift = 24 - 8 * p;
        // zero the 4 private hists
        #pragma unroll
        for (int z = 0; z < 4; ++z) hist[z][t & 255] = 0;  // t<256: each thread zeroes 4
        __syncthreads();
        #pragma unroll
        for (int s = 0; s < 16; ++s){
            unsigned kv = k4[s];
            unsigned grp = (shift >= 24) ? 0u : (kv >> (shift + 8));
            if (grp == prefix)
                atomicAdd(&hist[wid][(kv >> shift) & 255u], 1u);
        }
        __syncthreads();
        if (t < 64){
            unsigned c0 = hist[0][4*t+0] + hist[1][4*t+0] + hist[2][4*t+0] + hist[3][4*t+0];
            unsigned c1 = hist[0][4*t+1] + hist[1][4*t+1] + hist[2][4*t+1] + hist[3][4*t+1];
            unsigned c2 = hist[0][4*t+2] + hist[1][4*t+2] + hist[2][4*t+2] + hist[3][4*t+2];
            unsigned c3 = hist[0][4*t+3] + hist[1][4*t+3] + hist[2][4*t+3] + hist[3][4*t+3];
            unsigned s0 = c0, s1 = s0 + c1, s2 = s1 + c2, s3 = s2 + c3;
            unsigned scan = s3;
            #pragma unroll
            for (int off = 1; off < 64; off <<= 1){
                unsigned nv = __shfl_up(scan, off);
                if (t >= off) scan += nv;
            }
            unsigned excl = scan - s3;
            unsigned cb0 = excl,      ci0 = excl + s0;
            unsigned cb1 = excl + s0, ci1 = excl + s1;
            unsigned cb2 = excl + s1, ci2 = excl + s2;
            unsigned cb3 = excl + s2, ci3 = excl + s3;
            if (cb0 < need && ci0 >= need){ sSel = 4*t+0; sBelow = cb0; }
            if (cb1 < need && ci1 >= need){ sSel = 4*t+1; sBelow = cb1; }
            if (cb2 < need && ci2 >= need){ sSel = 4*t+2; sBelow = cb2; }
            if (cb3 < need && ci3 >= need){ sSel = 4*t+3; sBelow = cb3; }
        }
        __syncthreads();
        prefix = (prefix << 8) | sSel;
        need  -= sBelow;
        // next writes to sSel/hist occur only after 2 more barriers -> safe
    }
    unsigned T4 = prefix;     // exact key4 of the 32nd-smallest (by key4 rank)

    if (t == 0) sOcnt = 0;
    __syncthreads();
    #pragma unroll
    for (int s = 0; s < 16; ++s){
        if (k4[s] < T4){
            int pos = atomicAdd(&sOcnt, 1);
            idx_out[(size_t)node * KNNK + pos] = (s << 8) + t;
        }
    }
    __syncthreads();
    int C = sOcnt;            // == 32 - need
    // boundary group: key4 == T4; take `need` smallest by (d_bits, j).
    unsigned long long lastk = 0;   // compare against mkey = key+1 (>=1)
    for (unsigned r = 0; r < need; ++r){
        unsigned long long lmin = ~0ull;
        #pragma unroll
        for (int s = 0; s < 16; ++s){
            if (k4[s] == T4){
                unsigned long long mk =
                    (((unsigned long long)db[s] << 32) | (unsigned)((s << 8) + t)) + 1ull;
                if (mk > lastk && mk < lmin) lmin = mk;
            }
        }
        #pragma unroll
        for (int off = 32; off > 0; off >>= 1){
            unsigned long long o = __shfl_xor(lmin, off);
            if (o < lmin) lmin = o;
        }
        if (lane == 0) wred64[wid] = lmin;
        __syncthreads();
        if (t == 0){
            unsigned long long m = wred64[0];
            if (wred64[1] < m) m = wred64[1];
            if (wred64[2] < m) m = wred64[2];
            if (wred64[3] < m) m = wred64[3];
            sWin64 = m;
            idx_out[(size_t)node * KNNK + C + r] = (int)(unsigned)((m - 1ull) & 0xffffffffull);
        }
        __syncthreads();
        lastk = sWin64;
    }
}

// ---------------------------------------------------------------- K2: P-GEMM (per batch)
__global__ __launch_bounds__(256) void p_gemm(const float* __restrict__ feats_b,
                                              const float* __restrict__ We1,
                                              unsigned short* __restrict__ P){
    __shared__ float As[64][68];
    __shared__ float Bs[64][68];
    int t = threadIdx.x;
    int m0 = blockIdx.x << 6;
    int n0 = blockIdx.y << 6;
    int half = blockIdx.z;
    const float* Wb = We1 + (size_t)half * DIM * H1N;

    int tr = (t >> 4) << 2;
    int tc = (t & 15) << 2;
    float acc[4][4] = {};

    for (int kk = 0; kk < DIM; kk += 64){
        for (int e = t; e < 64*64; e += 256){
            int r = e >> 6, c = e & 63;
            As[r][c] = feats_b[(size_t)(m0 + r) * DIM + kk + c];
        }
        for (int e = t; e < 64*64; e += 256){
            int r = e >> 6, c = e & 63;
            int n = n0 + c;
            Bs[r][c] = (n < H1N) ? Wb[(size_t)(kk + r) * H1N + n] : 0.f;
        }
        __syncthreads();
        #pragma unroll 8
        for (int k = 0; k < 64; ++k){
            float a0 = As[tr+0][k], a1 = As[tr+1][k], a2 = As[tr+2][k], a3 = As[tr+3][k];
            float b0 = Bs[k][tc+0], b1 = Bs[k][tc+1], b2 = Bs[k][tc+2], b3 = Bs[k][tc+3];
            acc[0][0] += a0*b0; acc[0][1] += a0*b1; acc[0][2] += a0*b2; acc[0][3] += a0*b3;
            acc[1][0] += a1*b0; acc[1][1] += a1*b1; acc[1][2] += a1*b2; acc[1][3] += a1*b3;
            acc[2][0] += a2*b0; acc[2][1] += a2*b1; acc[2][2] += a2*b2; acc[2][3] += a2*b3;
            acc[3][0] += a3*b0; acc[3][1] += a3*b1; acc[3][2] += a3*b2; acc[3][3] += a3*b3;
        }
        __syncthreads();
    }
    #pragma unroll
    for (int ii = 0; ii < 4; ++ii)
        #pragma unroll
        for (int jj = 0; jj < 4; ++jj){
            int n = n0 + tc + jj;
            if (n < CPAD)
                P[(size_t)(m0 + tr + ii) * PROW + (size_t)half * CPAD + n] = f2us(acc[ii][jj]);
        }
}

// ---------------------------------------------------------------- K3: edges (MFMA, per batch)
__global__ __launch_bounds__(256, 3) void edge_kernel(
        int b,
        const float* __restrict__ coors, const float* __restrict__ We1,
        const float* __restrict__ be1,   const float* __restrict__ We2,
        const float* __restrict__ be2,   const float* __restrict__ Wc1,
        const float* __restrict__ bc1,   const float* __restrict__ Wc2,
        const float* __restrict__ bc2,   const int*  __restrict__ idx,
        const unsigned short* __restrict__ P, float* __restrict__ mi_out,
        float* __restrict__ coors_out){
    __shared__ unsigned short sW1fA[CPAD * 8];
    __shared__ unsigned short sW1f8[CPAD];
    __shared__ unsigned short sWe2A[16 * 552];
    __shared__ float          sbe1[CPAD];
    __shared__ unsigned short sWc1A[64 * 32];
    __shared__ float sbc1v[64], swc2v[64], sbe2v[16];
    __shared__ unsigned short sFeT[4][32 * 16];
    __shared__ unsigned short trans[4][32 * 40];
    __shared__ unsigned short sM[4][32 * 16];

    int t = threadIdx.x, lane = t & 63, wid = t >> 6;
    int i = (blockIdx.x << 2) + wid;
    int gnode = (b << 12) + i;

    for (int e = t; e < CPAD * 8; e += 256){
        int c = e >> 3, f = e & 7;
        sW1fA[e] = (c < H1N) ? f2us(We1[(size_t)(256 + f) * H1N + c]) : 0;
    }
    for (int e = t; e < CPAD; e += 256){
        sW1f8[e] = (e < H1N) ? f2us(We1[(size_t)264 * H1N + e]) : 0;
        sbe1[e]  = (e < H1N) ? be1[e] : 0.f;
    }
    for (int o = 0; o < 16; ++o)
        for (int c = t; c < 552; c += 256)
            sWe2A[o * 552 + c] = (c < H1N) ? f2us(We2[(size_t)c * 16 + o]) : 0;
    for (int e = t; e < 64 * 32; e += 256){
        int u = e >> 5, k = e & 31;
        sWc1A[e] = (k < 16) ? f2us(Wc1[(size_t)k * 64 + u]) : 0;
    }
    if (t < 64){ sbc1v[t] = bc1[t]; swc2v[t] = Wc2[t]; }
    if (t < 16) sbe2v[t] = be2[t];

    const float* cb = coors + (size_t)b * NN * 3;
    float qx = cb[i*3+0], qy = cb[i*3+1], qz = cb[i*3+2];
    int jme = 0; float rx = 0.f, ry = 0.f, rz = 0.f;
    if (lane < 32){
        jme = idx[(size_t)gnode * KNNK + lane];
        rx = qx - cb[jme*3+0]; ry = qy - cb[jme*3+1]; rz = qz - cb[jme*3+2];
        float d = rx*rx + ry*ry + rz*rz;
        unsigned short fr[16];
        fr[0] = f2us(sinf(d));         fr[1] = f2us(sinf(d * 0.5f));
        fr[2] = f2us(sinf(d * 0.25f)); fr[3] = f2us(sinf(d * 0.125f));
        fr[4] = f2us(cosf(d));         fr[5] = f2us(cosf(d * 0.5f));
        fr[6] = f2us(cosf(d * 0.25f)); fr[7] = f2us(cosf(d * 0.125f));
        fr[8] = f2us(d);
        #pragma unroll
        for (int z = 9; z < 16; ++z) fr[z] = 0;
        unsigned short* dst = &sFeT[wid][lane * 16];
        #pragma unroll
        for (int g = 0; g < 4; ++g)
            *(sh4*)&dst[g*4] = *(const sh4*)&fr[g*4];
    }
    int jall = __shfl(jme, lane & 31);
    __syncthreads();

    const unsigned short* Pirow = P + (size_t)i * PROW;
    const unsigned short* Pjrow = P + (size_t)jall * PROW + CPAD;

    int e31 = lane & 31, hi = lane >> 5;
    int e15 = lane & 15, q  = lane >> 4;

    fx4 accD0 = {0.f,0.f,0.f,0.f};
    fx4 accD1 = {0.f,0.f,0.f,0.f};

    for (int ch = 0; ch < 17; ++ch){
        int c0 = ch * 32;
        sh8 afrag;
        if (hi == 0) afrag = *(const sh8*)&sW1fA[(size_t)(c0 + e31) * 8];
        else { afrag = (sh8)0; afrag[0] = (short)sW1f8[c0 + e31]; }
        sh8 bfrag = *(const sh8*)&sFeT[wid][e31 * 16 + hi * 8];
        f32x16 cc;
        #pragma unroll
        for (int g = 0; g < 4; ++g){
            int cb4 = c0 + 8*g + 4*hi;
            us4 piu = *(const us4*)(Pirow + cb4);
            us4 pju = *(const us4*)(Pjrow + cb4);
            fx4 be  = *(const fx4*)&sbe1[cb4];
            cc[4*g+0] = us2f(piu.x) + us2f(pju.x) + be.x;
            cc[4*g+1] = us2f(piu.y) + us2f(pju.y) + be.y;
            cc[4*g+2] = us2f(piu.z) + us2f(pju.z) + be.z;
            cc[4*g+3] = us2f(piu.w) + us2f(pju.w) + be.w;
        }
        f32x16 h = __builtin_amdgcn_mfma_f32_32x32x16_bf16(afrag, bfrag, cc, 0, 0, 0);
        #pragma unroll
        for (int g = 0; g < 4; ++g){
            sh4 w4;
            w4[0] = (short)f2us(silu_f(h[4*g+0]));
            w4[1] = (short)f2us(silu_f(h[4*g+1]));
            w4[2] = (short)f2us(silu_f(h[4*g+2]));
            w4[3] = (short)f2us(silu_f(h[4*g+3]));
            *(sh4*)&trans[wid][e31 * 40 + 8*g + 4*hi] = w4;
        }
        asm volatile("s_waitcnt lgkmcnt(0)" ::: "memory");
        sh8 wa  = *(const sh8*)&sWe2A[e15 * 552 + c0 + q * 8];
        sh8 bt0 = *(const sh8*)&trans[wid][e15 * 40 + q * 8];
        sh8 bt1 = *(const sh8*)&trans[wid][(16 + e15) * 40 + q * 8];
        accD0 = __builtin_amdgcn_mfma_f32_16x16x32_bf16(wa, bt0, accD0, 0, 0, 0);
        accD1 = __builtin_amdgcn_mfma_f32_16x16x32_bf16(wa, bt1, accD1, 0, 0, 0);
    }

    fx4 be2q = *(const fx4*)&sbe2v[q * 4];
    float msum[4];
    sh4 m0s, m1s;
    #pragma unroll
    for (int r = 0; r < 4; ++r){
        float mv0 = silu_f(accD0[r] + be2q[r]);
        float mv1 = silu_f(accD1[r] + be2q[r]);
        m0s[r] = (short)f2us(mv0);
        m1s[r] = (short)f2us(mv1);
        msum[r] = mv0 + mv1;
    }
    *(sh4*)&sM[wid][e15 * 16 + q * 4]        = m0s;
    *(sh4*)&sM[wid][(16 + e15) * 16 + q * 4] = m1s;
    #pragma unroll
    for (int r = 0; r < 4; ++r){
        msum[r] += __shfl_xor(msum[r], 1);
        msum[r] += __shfl_xor(msum[r], 2);
        msum[r] += __shfl_xor(msum[r], 4);
        msum[r] += __shfl_xor(msum[r], 8);
    }
    if (e15 == 0){
        fx4 mv = { msum[0], msum[1], msum[2], msum[3] };
        *(fx4*)(mi_out + (size_t)gnode * MD + q * 4) = mv;
    }
    asm volatile("s_waitcnt lgkmcnt(0)" ::: "memory");

    float tsum0 = 0.f, tsum1 = 0.f;
    #pragma unroll
    for (int ut = 0; ut < 4; ++ut){
        sh8 wa3 = *(const sh8*)&sWc1A[(ut * 16 + e15) * 32 + q * 8];
        sh8 b0  = (q < 2) ? *(const sh8*)&sM[wid][e15 * 16 + q * 8]        : (sh8)0;
        sh8 b1  = (q < 2) ? *(const sh8*)&sM[wid][(16 + e15) * 16 + q * 8] : (sh8)0;
        fx4 a0 = {0.f,0.f,0.f,0.f};
        fx4 a1 = {0.f,0.f,0.f,0.f};
        a0 = __builtin_amdgcn_mfma_f32_16x16x32_bf16(wa3, b0, a0, 0, 0, 0);
        a1 = __builtin_amdgcn_mfma_f32_16x16x32_bf16(wa3, b1, a1, 0, 0, 0);
        fx4 bc1q = *(const fx4*)&sbc1v[ut * 16 + q * 4];
        fx4 wcq  = *(const fx4*)&swc2v[ut * 16 + q * 4];
        #pragma unroll
        for (int r = 0; r < 4; ++r){
            tsum0 += silu_f(a0[r] + bc1q[r]) * wcq[r];
            tsum1 += silu_f(a1[r] + bc1q[r]) * wcq[r];
        }
    }
    tsum0 += __shfl_xor(tsum0, 16); tsum0 += __shfl_xor(tsum0, 32);
    tsum1 += __shfl_xor(tsum1, 16); tsum1 += __shfl_xor(tsum1, 32);
    float cw = ((lane < 16) ? tsum0 : tsum1) + bc2[0];

    float cx = cw * rx, cy = cw * ry, cz = cw * rz;
    #pragma unroll
    for (int off = 1; off <= 32; off <<= 1){
        cx += __shfl_xor(cx, off);
        cy += __shfl_xor(cy, off);
        cz += __shfl_xor(cz, off);
    }
    if (lane == 0){
        coors_out[(size_t)gnode * 3 + 0] = cx + qx;
        coors_out[(size_t)gnode * 3 + 1] = cy + qy;
        coors_out[(size_t)gnode * 3 + 2] = cz + qz;
    }
}

// ---------------------------------------------------------------- K4: node MLP
__global__ __launch_bounds__(256) void node_kernel(
        const float* __restrict__ feats, const float* __restrict__ m_i,
        const float* __restrict__ Wn1,   const float* __restrict__ bn1,
        const float* __restrict__ Wn2,   const float* __restrict__ bn2,
        float* __restrict__ out){
    __shared__ float X[8][144];
    __shared__ float Hs[8][256];
    int t = threadIdx.x;
    int g0 = blockIdx.x << 3;

    for (int e = t; e < 8 * DIM; e += 256){
        int nd = e >> 7, c = e & 127;
        X[nd][c] = feats[(size_t)(g0 + nd) * DIM + c];
    }
    if (t < 128){
        int nd = t >> 4, c = t & 15;
        X[nd][DIM + c] = m_i[(size_t)(g0 + nd) * MD + c];
    }
    __syncthreads();

    float acc[8] = {};
    for (int r = 0; r < 144; ++r){
        float w = Wn1[(size_t)r * 256 + t];
        #pragma unroll
        for (int nd = 0; nd < 8; ++nd) acc[nd] += X[nd][r] * w;
    }
    float bb = bn1[t];
    #pragma unroll
    for (int nd = 0; nd < 8; ++nd) Hs[nd][t] = silu_f(acc[nd] + bb);
    __syncthreads();

    int c = t & 127, g = t >> 7;
    float a2[4] = {};
    for (int r = 0; r < 256; ++r){
        float w = Wn2[(size_t)r * DIM + c];
        #pragma unroll
        for (int u = 0; u < 4; ++u) a2[u] += Hs[g*4 + u][r] * w;
    }
    float b2v = bn2[c];
    #pragma unroll
    for (int u = 0; u < 4; ++u){
        int nd = g*4 + u;
        out[(size_t)(g0 + nd) * DIM + c] = a2[u] + b2v + X[nd][c];
    }
}

// ---------------------------------------------------------------- launch
extern "C" void kernel_launch(void* const* d_in, const int* in_sizes, int n_in,
                              void* d_out, int out_size, void* d_ws, size_t ws_size,
                              hipStream_t stream){
    char* ws = (char*)d_ws;
    size_t off = 0;
    auto alloc = [&](size_t bytes) -> char* {
        off = (off + 511) & ~(size_t)511;
        char* p = ws + off;
        off += bytes;
        return p;
    };

    int* flags = (int*)alloc(14 * 4);

    // contiguous fp32 conversion region
    ConvTab tab;
    int total = 0;
    for (int i = 0; i < 14; ++i){ tab.prefix[i] = total; total += in_sizes[i]; }
    tab.prefix[14] = total;
    float* convBase = (float*)alloc((size_t)total * 4);
    int doff = 0;
    for (int i = 0; i < 14; ++i){
        tab.src[i] = d_in[i];
        tab.dstoff[i] = doff;
        doff += in_sizes[i];
    }

    int*   idx    = (int*)  alloc((size_t)NODES * KNNK * 4);
    unsigned short* P = (unsigned short*) alloc((size_t)NN * PROW * 2);
    float* mi     = (float*)alloc((size_t)NODES * MD * 4);
    float* outf   = (float*)alloc((size_t)out_size * 4);

    Ptrs ps;
    for (int i = 0; i < 14; ++i){ ps.p[i] = d_in[i]; ps.n[i] = in_sizes[i]; }
    detect_kernel<<<14, 256, 0, stream>>>(ps, flags);
    convert_all<<<(total + 255) / 256, 256, 0, stream>>>(tab, flags, convBase);

    const float* feats = convBase + tab.dstoff[0];
    const float* coors = convBase + tab.dstoff[1];
    const float* We1 = convBase + tab.dstoff[2],  * be1 = convBase + tab.dstoff[3];
    const float* We2 = convBase + tab.dstoff[4],  * be2 = convBase + tab.dstoff[5];
    const float* Wc1 = convBase + tab.dstoff[6],  * bc1 = convBase + tab.dstoff[7];
    const float* Wc2 = convBase + tab.dstoff[8],  * bc2 = convBase + tab.dstoff[9];
    const float* Wn1 = convBase + tab.dstoff[10], * bn1 = convBase + tab.dstoff[11];
    const float* Wn2 = convBase + tab.dstoff[12], * bn2 = convBase + tab.dstoff[13];

    knn_kernel<<<NODES, 256, 0, stream>>>(coors, idx);
    for (int b = 0; b < 2; ++b){
        p_gemm<<<dim3(64, 9, 2), 256, 0, stream>>>(feats + (size_t)b * NN * DIM, We1, P);
        edge_kernel<<<NN/4, 256, 0, stream>>>(b, coors, We1, be1, We2, be2, Wc1, bc1,
                                              Wc2, bc2, idx, P, mi,
                                              outf + (size_t)NODES * DIM);
    }
    node_kernel<<<1024, 256, 0, stream>>>(feats, mi, Wn1, bn1, Wn2, bn2, outf);

    emit_kernel<<<(out_size + 255) / 256, 256, 0, stream>>>(outf, d_out, out_size, flags + 0);
}

// Round 6
// 336.622 us; speedup vs baseline: 3.0228x; 1.3728x over previous
//
#include <hip/hip_runtime.h>
#include <hip/hip_bf16.h>
#include <stdint.h>

typedef __hip_bfloat16 bf16;

using sh8    = __attribute__((ext_vector_type(8)))  short;
using sh4    = __attribute__((ext_vector_type(4)))  short;
using us4    = __attribute__((ext_vector_type(4)))  unsigned short;
using f32x16 = __attribute__((ext_vector_type(16))) float;
using fx4    = __attribute__((ext_vector_type(4)))  float;

#define NN    4096
#define NODES 8192
#define DIM   128
#define MD    16
#define KNNK  32
#define H1N   530
#define CPAD  544      // H1N padded to 17*32
#define PROW  1088     // [Pi 544 | Pj 544] per node, bf16

// weight-image offsets (in shorts)
#define OFF_W1FA 0      // [c][f0..7]    4352
#define OFF_W1F8 4352   // [c] f=8        544
#define OFF_WE2A 4896   // [o][c] s=552  8832
#define OFF_WC1A 13728  // [u][k] s=32   2048
#define OFF_BE2  15776  // fp32[16]        32
#define OFF_BC1  15808  // fp32[64]       128
#define OFF_WC2  15936  // fp32[64]       128
#define OFF_BC2  16064  // fp32[4]          8
#define WIMG_SH  16072  // 32144 B = 2009 float4
#define WIMG_F4  2009

__device__ __forceinline__ float b2f(bf16 x){ return __bfloat162float(x); }
__device__ __forceinline__ bf16  f2b(float x){ return __float2bfloat16(x); }
__device__ __forceinline__ float silu_f(float x){ return x / (1.f + __expf(-x)); }

__device__ __forceinline__ unsigned short f2us(float f){
    unsigned x = __float_as_uint(f);
    unsigned r = x + 0x7FFFu + ((x >> 16) & 1u);
    return (unsigned short)(r >> 16);
}
__device__ __forceinline__ float us2f(unsigned short u){
    return __uint_as_float(((unsigned)u) << 16);
}

// ---------------------------------------------------------------- K0: dtype detect
struct Ptrs { const void* p[14]; int n[14]; };

__global__ __launch_bounds__(256) void detect_kernel(Ptrs ps, int* flags){
    int tn = blockIdx.x;
    const bf16* s = (const bf16*)ps.p[tn];
    int n = ps.n[tn]; if (n > 8192) n = 8192;
    int bad = 0;
    for (int i = threadIdx.x; i < n; i += 256){
        float v = b2f(s[i]);
        if (!(fabsf(v) <= 64.f)) bad = 1;   // catches NaN/Inf too
    }
    __shared__ int sbad;
    if (threadIdx.x == 0) sbad = 0;
    __syncthreads();
    if (bad) atomicOr(&sbad, 1);
    __syncthreads();
    if (threadIdx.x == 0) flags[tn] = sbad;   // 1 = fp32, 0 = bf16
}

// ---------------------------------------------------------------- K0b: fused convert
struct ConvTab {
    const void* src[14];
    int dstoff[14];
    int prefix[15];
};

__global__ __launch_bounds__(256) void convert_all(ConvTab tab,
                                                   const int* __restrict__ flags,
                                                   float* __restrict__ base){
    int gid = blockIdx.x * 256 + threadIdx.x;
    if (gid >= tab.prefix[14]) return;
    int tn = 0;
    #pragma unroll
    for (int k = 1; k < 14; ++k)
        if (gid >= tab.prefix[k]) tn = k;
    int local = gid - tab.prefix[tn];
    int f = flags[tn];
    float v = f ? ((const float*)tab.src[tn])[local]
                : b2f(((const bf16*)tab.src[tn])[local]);
    base[tab.dstoff[tn] + local] = v;
}

// ---------------------------------------------------------------- K0c: weight prep
// Builds: gwimg (bf16 weight image + fp32 biases), We1T bf16 [1088][128],
// fBF bf16 [8192][128].
__global__ __launch_bounds__(256) void prep_kernel(
        const float* __restrict__ We1, const float* __restrict__ We2,
        const float* __restrict__ Wc1, const float* __restrict__ be2,
        const float* __restrict__ bc1, const float* __restrict__ Wc2,
        const float* __restrict__ bc2, const float* __restrict__ feats,
        unsigned short* __restrict__ gwimg,
        unsigned short* __restrict__ We1T,
        unsigned short* __restrict__ fBF){
    int gid = blockIdx.x * 256 + threadIdx.x;
    if (gid < 4352){
        int c = gid >> 3, f = gid & 7;
        gwimg[OFF_W1FA + gid] = (c < H1N) ? f2us(We1[(size_t)(256 + f) * H1N + c]) : 0;
    } else if (gid < 4896){
        int c = gid - 4352;
        gwimg[OFF_W1F8 + c] = (c < H1N) ? f2us(We1[(size_t)264 * H1N + c]) : 0;
    } else if (gid < 13728){
        int e = gid - 4896; int o = e / 552, c = e - o * 552;
        gwimg[OFF_WE2A + e] = (c < H1N) ? f2us(We2[(size_t)c * 16 + o]) : 0;
    } else if (gid < 15776){
        int e = gid - 13728; int u = e >> 5, k = e & 31;
        gwimg[OFF_WC1A + e] = (k < 16) ? f2us(Wc1[(size_t)k * 64 + u]) : 0;
    } else if (gid < 15792){
        ((float*)(gwimg + OFF_BE2))[gid - 15776] = be2[gid - 15776];
    } else if (gid < 15856){
        ((float*)(gwimg + OFF_BC1))[gid - 15792] = bc1[gid - 15792];
    } else if (gid < 15920){
        ((float*)(gwimg + OFF_WC2))[gid - 15856] = Wc2[gid - 15856];
    } else if (gid < 15924){
        int z = gid - 15920;
        ((float*)(gwimg + OFF_BC2))[z] = (z == 0) ? bc2[0] : 0.f;
    } else if (gid >= 16384 && gid < 16384 + 1088 * 128){
        int e = gid - 16384; int n = e >> 7, k = e & 127;
        float v;
        if (n < CPAD) v = (n < H1N) ? We1[(size_t)k * H1N + n] : 0.f;
        else { int n2 = n - CPAD; v = (n2 < H1N) ? We1[(size_t)(128 + k) * H1N + n2] : 0.f; }
        We1T[e] = f2us(v);
    } else if (gid >= 155648 && gid < 155648 + NODES * DIM){
        int e = gid - 155648;
        fBF[e] = f2us(feats[e]);
    }
}

// ---------------------------------------------------------------- K5: emit output
__global__ __launch_bounds__(256) void emit_kernel(const float* __restrict__ outf,
                                                   void* __restrict__ dout, int n,
                                                   const int* __restrict__ flag){
    int f = *flag;
    int i = blockIdx.x * 256 + threadIdx.x;
    if (i < n){
        if (f) ((float*)dout)[i] = outf[i];
        else   ((bf16*)dout)[i]  = f2b(outf[i]);
    }
}

// ---------------------------------------------------------------- K1: KNN radix select
__global__ __launch_bounds__(256) void knn_kernel(const float* __restrict__ coors,
                                                  int* __restrict__ idx_out){
    __shared__ unsigned hist[4][256];
    __shared__ unsigned sSel, sBelow;
    __shared__ int  sOcnt;
    __shared__ unsigned long long wred64[4];
    __shared__ unsigned long long sWin64;

    int node = blockIdx.x;
    int b = node >> 12, i = node & (NN - 1);
    const float* cb = coors + (size_t)b * NN * 3;
    int t = threadIdx.x, lane = t & 63, wid = t >> 6;

    float qx = cb[i*3+0], qy = cb[i*3+1], qz = cb[i*3+2];

    unsigned db[16];
    unsigned k4[16];
    #pragma unroll
    for (int s = 0; s < 16; ++s){
        int j = (s << 8) + t;
        float dx = qx - cb[j*3+0];
        float dy = qy - cb[j*3+1];
        float dz = qz - cb[j*3+2];
        float d  = dx*dx + dy*dy + dz*dz;
        float d2 = d * d;
        db[s] = __float_as_uint(d);
        k4[s] = __float_as_uint(d2 * d2);
    }

    unsigned prefix = 0, need = KNNK;
    #pragma unroll
    for (int p = 0; p < 4; ++p){
        const int shift = 24 - 8 * p;
        #pragma unroll
        for (int z = 0; z < 4; ++z) hist[z][t & 255] = 0;
        __syncthreads();
        #pragma unroll
        for (int s = 0; s < 16; ++s){
            unsigned kv = k4[s];
            unsigned grp = (shift >= 24) ? 0u : (kv >> (shift + 8));
            if (grp == prefix)
                atomicAdd(&hist[wid][(kv >> shift) & 255u], 1u);
        }
        __syncthreads();
        if (t < 64){
            unsigned c0 = hist[0][4*t+0] + hist[1][4*t+0] + hist[2][4*t+0] + hist[3][4*t+0];
            unsigned c1 = hist[0][4*t+1] + hist[1][4*t+1] + hist[2][4*t+1] + hist[3][4*t+1];
            unsigned c2 = hist[0][4*t+2] + hist[1][4*t+2] + hist[2][4*t+2] + hist[3][4*t+2];
            unsigned c3 = hist[0][4*t+3] + hist[1][4*t+3] + hist[2][4*t+3] + hist[3][4*t+3];
            unsigned s0 = c0, s1 = s0 + c1, s2 = s1 + c2, s3 = s2 + c3;
            unsigned scan = s3;
            #pragma unroll
            for (int off = 1; off < 64; off <<= 1){
                unsigned nv = __shfl_up(scan, off);
                if (t >= off) scan += nv;
            }
            unsigned excl = scan - s3;
            unsigned cb0 = excl,      ci0 = excl + s0;
            unsigned cb1 = excl + s0, ci1 = excl + s1;
            unsigned cb2 = excl + s1, ci2 = excl + s2;
            unsigned cb3 = excl + s2, ci3 = excl + s3;
            if (cb0 < need && ci0 >= need){ sSel = 4*t+0; sBelow = cb0; }
            if (cb1 < need && ci1 >= need){ sSel = 4*t+1; sBelow = cb1; }
            if (cb2 < need && ci2 >= need){ sSel = 4*t+2; sBelow = cb2; }
            if (cb3 < need && ci3 >= need){ sSel = 4*t+3; sBelow = cb3; }
        }
        __syncthreads();
        prefix = (prefix << 8) | sSel;
        need  -= sBelow;
    }
    unsigned T4 = prefix;

    if (t == 0) sOcnt = 0;
    __syncthreads();
    #pragma unroll
    for (int s = 0; s < 16; ++s){
        if (k4[s] < T4){
            int pos = atomicAdd(&sOcnt, 1);
            idx_out[(size_t)node * KNNK + pos] = (s << 8) + t;
        }
    }
    __syncthreads();
    int C = sOcnt;
    unsigned long long lastk = 0;
    for (unsigned r = 0; r < need; ++r){
        unsigned long long lmin = ~0ull;
        #pragma unroll
        for (int s = 0; s < 16; ++s){
            if (k4[s] == T4){
                unsigned long long mk =
                    (((unsigned long long)db[s] << 32) | (unsigned)((s << 8) + t)) + 1ull;
                if (mk > lastk && mk < lmin) lmin = mk;
            }
        }
        #pragma unroll
        for (int off = 32; off > 0; off >>= 1){
            unsigned long long o = __shfl_xor(lmin, off);
            if (o < lmin) lmin = o;
        }
        if (lane == 0) wred64[wid] = lmin;
        __syncthreads();
        if (t == 0){
            unsigned long long m = wred64[0];
            if (wred64[1] < m) m = wred64[1];
            if (wred64[2] < m) m = wred64[2];
            if (wred64[3] < m) m = wred64[3];
            sWin64 = m;
            idx_out[(size_t)node * KNNK + C + r] = (int)(unsigned)((m - 1ull) & 0xffffffffull);
        }
        __syncthreads();
        lastk = sWin64;
    }
}

// ---------------------------------------------------------------- K2: P-GEMM (MFMA, per batch)
// P[m][n] = feats_b[m] @ We1T[n] (+ be1[n] folded into the Pi half).
// grid (32, 34); wave = one 32x32 tile, K=128 in 8 MFMAs; no LDS.
__global__ __launch_bounds__(256) void p_gemm(const unsigned short* __restrict__ fBF_b,
                                              const unsigned short* __restrict__ We1T,
                                              const float* __restrict__ be1,
                                              unsigned short* __restrict__ P){
    int t = threadIdx.x, lane = t & 63, wid = t >> 6;
    int e31 = lane & 31, hi = lane >> 5;
    int mW = (blockIdx.x << 7) + (wid << 5);
    int n0 = blockIdx.y << 5;

    const unsigned short* Arow = fBF_b + (size_t)(mW + e31) * DIM + hi * 8;
    const unsigned short* Brow = We1T  + (size_t)(n0 + e31) * DIM + hi * 8;

    f32x16 acc = {0.f,0.f,0.f,0.f,0.f,0.f,0.f,0.f,0.f,0.f,0.f,0.f,0.f,0.f,0.f,0.f};
    #pragma unroll
    for (int kc = 0; kc < 8; ++kc){
        sh8 a  = *(const sh8*)(Arow + kc * 16);
        sh8 bv = *(const sh8*)(Brow + kc * 16);
        acc = __builtin_amdgcn_mfma_f32_32x32x16_bf16(a, bv, acc, 0, 0, 0);
    }
    int n = n0 + e31;
    float beadd = 0.f;
    if (n < CPAD) beadd = (n < H1N) ? be1[n] : 0.f;   // fold be1 into Pi half
    #pragma unroll
    for (int g = 0; g < 4; ++g)
        #pragma unroll
        for (int r = 0; r < 4; ++r){
            int m = mW + 8*g + 4*hi + r;
            P[(size_t)m * PROW + n] = f2us(acc[4*g + r] + beadd);
        }
}

// ---------------------------------------------------------------- K3: edges (MFMA, per batch)
// 4 nodes/block, 1 wave/node; coalesced weight-image staging; Pi/Pj prefetch.
__global__ __launch_bounds__(256, 3) void edge_kernel(
        int b, const float* __restrict__ coors, const int* __restrict__ idx,
        const unsigned short* __restrict__ gwimg,
        const unsigned short* __restrict__ P,
        float* __restrict__ mi_out, float* __restrict__ coors_out){
    __shared__ __align__(16) unsigned short wimg[WIMG_SH];
    __shared__ __align__(16) unsigned short sFeT[4][512];    // [e][f] bf16
    __shared__ __align__(16) unsigned short trans[4][1280];  // [e][c_loc] s=40; head reused as sM

    int t = threadIdx.x, lane = t & 63, wid = t >> 6;
    int i = (blockIdx.x << 2) + wid;
    int gnode = (b << 12) + i;

    {   // stage weight image: one contiguous coalesced copy
        const float4* src = (const float4*)gwimg;
        float4* dst = (float4*)wimg;
        for (int e = t; e < WIMG_F4; e += 256) dst[e] = src[e];
    }

    const float* cb = coors + (size_t)b * NN * 3;
    float qx = cb[i*3+0], qy = cb[i*3+1], qz = cb[i*3+2];
    int jme = 0; float rx = 0.f, ry = 0.f, rz = 0.f;
    if (lane < 32){
        jme = idx[(size_t)gnode * KNNK + lane];
        rx = qx - cb[jme*3+0]; ry = qy - cb[jme*3+1]; rz = qz - cb[jme*3+2];
        float d = rx*rx + ry*ry + rz*rz;
        unsigned short fr[16];
        fr[0] = f2us(sinf(d));         fr[1] = f2us(sinf(d * 0.5f));
        fr[2] = f2us(sinf(d * 0.25f)); fr[3] = f2us(sinf(d * 0.125f));
        fr[4] = f2us(cosf(d));         fr[5] = f2us(cosf(d * 0.5f));
        fr[6] = f2us(cosf(d * 0.25f)); fr[7] = f2us(cosf(d * 0.125f));
        fr[8] = f2us(d);
        #pragma unroll
        for (int z = 9; z < 16; ++z) fr[z] = 0;
        unsigned short* dst = &sFeT[wid][lane * 16];
        #pragma unroll
        for (int g = 0; g < 4; ++g)
            *(sh4*)&dst[g*4] = *(const sh4*)&fr[g*4];
    }
    int jall = __shfl(jme, lane & 31);
    __syncthreads();

    const unsigned short* Pirow = P + (size_t)i * PROW;
    const unsigned short* Pjrow = P + (size_t)jall * PROW + CPAD;

    int e31 = lane & 31, hi = lane >> 5;
    int e15 = lane & 15, q  = lane >> 4;

    const float* sbe2v = (const float*)(wimg + OFF_BE2);
    const float* sbc1v = (const float*)(wimg + OFF_BC1);
    const float* swc2v = (const float*)(wimg + OFF_WC2);

    sh8 bfragC = *(const sh8*)&sFeT[wid][e31 * 16 + hi * 8];   // chunk-invariant

    fx4 accD0 = {0.f,0.f,0.f,0.f};
    fx4 accD1 = {0.f,0.f,0.f,0.f};

    us4 piC[4], pjC[4];
    #pragma unroll
    for (int g = 0; g < 4; ++g){
        int cb4 = 8*g + 4*hi;
        piC[g] = *(const us4*)(Pirow + cb4);
        pjC[g] = *(const us4*)(Pjrow + cb4);
    }

    for (int ch = 0; ch < 17; ++ch){
        int c0 = ch * 32;
        sh8 afrag;
        if (hi == 0) afrag = *(const sh8*)&wimg[OFF_W1FA + (c0 + e31) * 8];
        else { afrag = (sh8)0; afrag[0] = (short)wimg[OFF_W1F8 + c0 + e31]; }

        f32x16 cc;
        #pragma unroll
        for (int g = 0; g < 4; ++g){
            cc[4*g+0] = us2f(piC[g].x) + us2f(pjC[g].x);
            cc[4*g+1] = us2f(piC[g].y) + us2f(pjC[g].y);
            cc[4*g+2] = us2f(piC[g].z) + us2f(pjC[g].z);
            cc[4*g+3] = us2f(piC[g].w) + us2f(pjC[g].w);
        }
        f32x16 h = __builtin_amdgcn_mfma_f32_32x32x16_bf16(afrag, bfragC, cc, 0, 0, 0);

        // prefetch next chunk (issued before the lgkm barrier)
        int c0n = (ch < 16) ? (c0 + 32) : 0;
        us4 piN[4], pjN[4];
        #pragma unroll
        for (int g = 0; g < 4; ++g){
            int cb4 = c0n + 8*g + 4*hi;
            piN[g] = *(const us4*)(Pirow + cb4);
            pjN[g] = *(const us4*)(Pjrow + cb4);
        }

        #pragma unroll
        for (int g = 0; g < 4; ++g){
            sh4 w4;
            w4[0] = (short)f2us(silu_f(h[4*g+0]));
            w4[1] = (short)f2us(silu_f(h[4*g+1]));
            w4[2] = (short)f2us(silu_f(h[4*g+2]));
            w4[3] = (short)f2us(silu_f(h[4*g+3]));
            *(sh4*)&trans[wid][e31 * 40 + 8*g + 4*hi] = w4;
        }
        asm volatile("s_waitcnt lgkmcnt(0)" ::: "memory");

        sh8 wa  = *(const sh8*)&wimg[OFF_WE2A + e15 * 552 + c0 + q * 8];
        sh8 bt0 = *(const sh8*)&trans[wid][e15 * 40 + q * 8];
        sh8 bt1 = *(const sh8*)&trans[wid][(16 + e15) * 40 + q * 8];
        accD0 = __builtin_amdgcn_mfma_f32_16x16x32_bf16(wa, bt0, accD0, 0, 0, 0);
        accD1 = __builtin_amdgcn_mfma_f32_16x16x32_bf16(wa, bt1, accD1, 0, 0, 0);

        #pragma unroll
        for (int g = 0; g < 4; ++g){ piC[g] = piN[g]; pjC[g] = pjN[g]; }
    }

    // ---- m = silu(OUT2 + be2); sM (aliases trans head); m_i butterfly ----
    fx4 be2q = *(const fx4*)&sbe2v[q * 4];
    float msum[4];
    sh4 m0s, m1s;
    #pragma unroll
    for (int r = 0; r < 4; ++r){
        float mv0 = silu_f(accD0[r] + be2q[r]);
        float mv1 = silu_f(accD1[r] + be2q[r]);
        m0s[r] = (short)f2us(mv0);
        m1s[r] = (short)f2us(mv1);
        msum[r] = mv0 + mv1;
    }
    unsigned short* sMw = &trans[wid][0];
    *(sh4*)&sMw[e15 * 16 + q * 4]        = m0s;
    *(sh4*)&sMw[(16 + e15) * 16 + q * 4] = m1s;
    #pragma unroll
    for (int r = 0; r < 4; ++r){
        msum[r] += __shfl_xor(msum[r], 1);
        msum[r] += __shfl_xor(msum[r], 2);
        msum[r] += __shfl_xor(msum[r], 4);
        msum[r] += __shfl_xor(msum[r], 8);
    }
    if (e15 == 0){
        fx4 mv = { msum[0], msum[1], msum[2], msum[3] };
        *(fx4*)(mi_out + (size_t)gnode * MD + q * 4) = mv;
    }
    asm volatile("s_waitcnt lgkmcnt(0)" ::: "memory");

    // ---- phase E: coors MLP ----
    float tsum0 = 0.f, tsum1 = 0.f;
    #pragma unroll
    for (int ut = 0; ut < 4; ++ut){
        sh8 wa3 = *(const sh8*)&wimg[OFF_WC1A + (ut * 16 + e15) * 32 + q * 8];
        sh8 b0  = (q < 2) ? *(const sh8*)&sMw[e15 * 16 + q * 8]        : (sh8)0;
        sh8 b1  = (q < 2) ? *(const sh8*)&sMw[(16 + e15) * 16 + q * 8] : (sh8)0;
        fx4 a0 = {0.f,0.f,0.f,0.f};
        fx4 a1 = {0.f,0.f,0.f,0.f};
        a0 = __builtin_amdgcn_mfma_f32_16x16x32_bf16(wa3, b0, a0, 0, 0, 0);
        a1 = __builtin_amdgcn_mfma_f32_16x16x32_bf16(wa3, b1, a1, 0, 0, 0);
        fx4 bc1q = *(const fx4*)&sbc1v[ut * 16 + q * 4];
        fx4 wcq  = *(const fx4*)&swc2v[ut * 16 + q * 4];
        #pragma unroll
        for (int r = 0; r < 4; ++r){
            tsum0 += silu_f(a0[r] + bc1q[r]) * wcq[r];
            tsum1 += silu_f(a1[r] + bc1q[r]) * wcq[r];
        }
    }
    tsum0 += __shfl_xor(tsum0, 16); tsum0 += __shfl_xor(tsum0, 32);
    tsum1 += __shfl_xor(tsum1, 16); tsum1 += __shfl_xor(tsum1, 32);
    float bc2v = ((const float*)(wimg + OFF_BC2))[0];
    float cw = ((lane < 16) ? tsum0 : tsum1) + bc2v;

    float cx = cw * rx, cy = cw * ry, cz = cw * rz;
    #pragma unroll
    for (int off = 1; off <= 32; off <<= 1){
        cx += __shfl_xor(cx, off);
        cy += __shfl_xor(cy, off);
        cz += __shfl_xor(cz, off);
    }
    if (lane == 0){
        coors_out[(size_t)gnode * 3 + 0] = cx + qx;
        coors_out[(size_t)gnode * 3 + 1] = cy + qy;
        coors_out[(size_t)gnode * 3 + 2] = cz + qz;
    }
}

// ---------------------------------------------------------------- K4: node MLP
__global__ __launch_bounds__(256) void node_kernel(
        const float* __restrict__ feats, const float* __restrict__ m_i,
        const float* __restrict__ Wn1,   const float* __restrict__ bn1,
        const float* __restrict__ Wn2,   const float* __restrict__ bn2,
        float* __restrict__ out){
    __shared__ float X[8][144];
    __shared__ float Hs[8][256];
    int t = threadIdx.x;
    int g0 = blockIdx.x << 3;

    for (int e = t; e < 8 * DIM; e += 256){
        int nd = e >> 7, c = e & 127;
        X[nd][c] = feats[(size_t)(g0 + nd) * DIM + c];
    }
    if (t < 128){
        int nd = t >> 4, c = t & 15;
        X[nd][DIM + c] = m_i[(size_t)(g0 + nd) * MD + c];
    }
    __syncthreads();

    float acc[8] = {};
    for (int r = 0; r < 144; ++r){
        float w = Wn1[(size_t)r * 256 + t];
        #pragma unroll
        for (int nd = 0; nd < 8; ++nd) acc[nd] += X[nd][r] * w;
    }
    float bb = bn1[t];
    #pragma unroll
    for (int nd = 0; nd < 8; ++nd) Hs[nd][t] = silu_f(acc[nd] + bb);
    __syncthreads();

    int c = t & 127, g = t >> 7;
    float a2[4] = {};
    for (int r = 0; r < 256; ++r){
        float w = Wn2[(size_t)r * DIM + c];
        #pragma unroll
        for (int u = 0; u < 4; ++u) a2[u] += Hs[g*4 + u][r] * w;
    }
    float b2v = bn2[c];
    #pragma unroll
    for (int u = 0; u < 4; ++u){
        int nd = g*4 + u;
        out[(size_t)(g0 + nd) * DIM + c] = a2[u] + b2v + X[nd][c];
    }
}

// ---------------------------------------------------------------- launch
extern "C" void kernel_launch(void* const* d_in, const int* in_sizes, int n_in,
                              void* d_out, int out_size, void* d_ws, size_t ws_size,
                              hipStream_t stream){
    char* ws = (char*)d_ws;
    size_t off = 0;
    auto alloc = [&](size_t bytes) -> char* {
        off = (off + 511) & ~(size_t)511;
        char* p = ws + off;
        off += bytes;
        return p;
    };

    int* flags = (int*)alloc(14 * 4);

    ConvTab tab;
    int total = 0;
    for (int i = 0; i < 14; ++i){ tab.prefix[i] = total; total += in_sizes[i]; }
    tab.prefix[14] = total;
    float* convBase = (float*)alloc((size_t)total * 4);
    int doff = 0;
    for (int i = 0; i < 14; ++i){
        tab.src[i] = d_in[i];
        tab.dstoff[i] = doff;
        doff += in_sizes[i];
    }

    unsigned short* gwimg = (unsigned short*)alloc((size_t)WIMG_SH * 2);
    unsigned short* We1T  = (unsigned short*)alloc((size_t)1088 * 128 * 2);
    unsigned short* fBF   = (unsigned short*)alloc((size_t)NODES * DIM * 2);
    int*   idx    = (int*)  alloc((size_t)NODES * KNNK * 4);
    unsigned short* P = (unsigned short*) alloc((size_t)NN * PROW * 2);
    float* mi     = (float*)alloc((size_t)NODES * MD * 4);
    float* outf   = (float*)alloc((size_t)out_size * 4);

    Ptrs ps;
    for (int i = 0; i < 14; ++i){ ps.p[i] = d_in[i]; ps.n[i] = in_sizes[i]; }
    detect_kernel<<<14, 256, 0, stream>>>(ps, flags);
    convert_all<<<(total + 255) / 256, 256, 0, stream>>>(tab, flags, convBase);

    const float* feats = convBase + tab.dstoff[0];
    const float* coors = convBase + tab.dstoff[1];
    const float* We1 = convBase + tab.dstoff[2],  * be1 = convBase + tab.dstoff[3];
    const float* We2 = convBase + tab.dstoff[4],  * be2 = convBase + tab.dstoff[5];
    const float* Wc1 = convBase + tab.dstoff[6],  * bc1 = convBase + tab.dstoff[7];
    const float* Wc2 = convBase + tab.dstoff[8],  * bc2 = convBase + tab.dstoff[9];
    const float* Wn1 = convBase + tab.dstoff[10], * bn1 = convBase + tab.dstoff[11];
    const float* Wn2 = convBase + tab.dstoff[12], * bn2 = convBase + tab.dstoff[13];

    prep_kernel<<<(155648 + NODES * DIM) / 256, 256, 0, stream>>>(
        We1, We2, Wc1, be2, bc1, Wc2, bc2, feats, gwimg, We1T, fBF);
    knn_kernel<<<NODES, 256, 0, stream>>>(coors, idx);
    for (int b = 0; b < 2; ++b){
        p_gemm<<<dim3(32, 34), 256, 0, stream>>>(fBF + (size_t)b * NN * DIM, We1T, be1, P);
        edge_kernel<<<NN/4, 256, 0, stream>>>(b, coors, idx, gwimg, P, mi,
                                              outf + (size_t)NODES * DIM);
    }
    node_kernel<<<1024, 256, 0, stream>>>(feats, mi, Wn1, bn1, Wn2, bn2, outf);

    emit_kernel<<<(out_size + 255) / 256, 256, 0, stream>>>(outf, d_out, out_size, flags + 0);
}